// Round 2
// baseline (445.727 us; speedup 1.0000x reference)
//
#include <hip/hip_runtime.h>
#include <hip/hip_bf16.h>
#include <math.h>

#define B 32
#define KLEN 2000
#define KDIM 512
#define QDIM 512
#define ADIM 512
#define VDIM 512
#define CONV_CH 10
#define CONV_K 201
#define NROWS (B*KLEN)

typedef __attribute__((ext_vector_type(8))) short bf16x8;
typedef __attribute__((ext_vector_type(4))) float f32x4;

__device__ __forceinline__ ushort f32_to_bf16(float f) {
    union { float f; unsigned int u; } v; v.f = f;
    unsigned int x = v.u;
    unsigned int r = (x + 0x7FFFu + ((x >> 16) & 1u)) >> 16;
    return (ushort)r;
}

__device__ __forceinline__ float fast_tanh(float x) {
    // tanh(x) = 1 - 2/(e^(2x)+1); stable at both extremes (inf -> 1, -inf -> -1)
    return 1.0f - 2.0f / (__expf(2.0f * x) + 1.0f);
}

// ---- K0: Wk f32 -> bf16 -------------------------------------------------
__global__ void k_cvt_wk(const float* __restrict__ Wk, ushort* __restrict__ wkb) {
    int i = blockIdx.x * 256 + threadIdx.x;
    if (i < ADIM * KDIM) wkb[i] = f32_to_bf16(Wk[i]);
}

// ---- K1: qproj[b][a] = dot(query[b], Wq[a]) -----------------------------
__global__ void k_qproj(const float* __restrict__ query, const float* __restrict__ Wq,
                        float* __restrict__ qproj) {
    int t = blockIdx.x * 256 + threadIdx.x;        // 16384
    int b = t >> 9, a = t & 511;
    const f32x4* q = (const f32x4*)(query + b * QDIM);
    const f32x4* w = (const f32x4*)(Wq + a * QDIM);
    float acc = 0.f;
    #pragma unroll 4
    for (int i = 0; i < 128; i++) {
        f32x4 qv = q[i], wv = w[i];
        acc += qv[0]*wv[0] + qv[1]*wv[1] + qv[2]*wv[2] + qv[3]*wv[3];
    }
    qproj[t] = acc;
}

// ---- K2: conv_feat[b][c][k] = SAME cross-correlation --------------------
__global__ void k_conv(const float* __restrict__ aw_prev, const float* __restrict__ conv_w,
                       float* __restrict__ cf) {
    int t = blockIdx.x * 256 + threadIdx.x;
    if (t >= B * CONV_CH * KLEN) return;
    int k = t % KLEN;
    int c = (t / KLEN) % CONV_CH;
    int b = t / (KLEN * CONV_CH);
    const float* aw = aw_prev + b * KLEN;
    const float* w  = conv_w + c * CONV_K;
    int lo = k - 100;
    int t0 = lo < 0 ? -lo : 0;
    int t1 = (lo + CONV_K > KLEN) ? (KLEN - lo) : CONV_K;
    float acc = 0.f;
    for (int tt = t0; tt < t1; tt++) acc += w[tt] * aw[lo + tt];
    cf[t] = acc;
}

// ---- K3: fused kproj GEMM + additive score ------------------------------
// e[b][k] = sum_a v[a] * tanh(kproj + bk[a] + qproj[b][a] + sum_c cf[b][c][k]*Wconv[a][c])
__global__ void k_main(const float* __restrict__ key, const ushort* __restrict__ wkb,
                       const float* __restrict__ qproj, const float* __restrict__ cf,
                       const float* __restrict__ bk, const float* __restrict__ vvec,
                       const float* __restrict__ Wconv, const int* __restrict__ mask,
                       float* __restrict__ e_out) {
    __shared__ char smem[16 * 1024];   // 16 a-rows x 512 d bf16, XOR-swizzled
    const int tid  = threadIdx.x;
    const int wave = tid >> 6, lane = tid & 63;
    const int l15 = lane & 15, lhi = lane >> 4;
    const int wrow0 = blockIdx.x * 64 + wave * 16;

    // Key fragments into registers (bf16). A-frag: row = l15, k = ds*32 + lhi*8 + j
    bf16x8 akey[16];
    {
        const float* kp = key + (size_t)(wrow0 + l15) * KDIM + lhi * 8;
        #pragma unroll
        for (int ds = 0; ds < 16; ds++) {
            f32x4 f0 = *(const f32x4*)(kp + ds * 32);
            f32x4 f1 = *(const f32x4*)(kp + ds * 32 + 4);
            union { bf16x8 v8; ushort u[8]; } pk;
            pk.u[0] = f32_to_bf16(f0[0]); pk.u[1] = f32_to_bf16(f0[1]);
            pk.u[2] = f32_to_bf16(f0[2]); pk.u[3] = f32_to_bf16(f0[3]);
            pk.u[4] = f32_to_bf16(f1[0]); pk.u[5] = f32_to_bf16(f1[1]);
            pk.u[6] = f32_to_bf16(f1[2]); pk.u[7] = f32_to_bf16(f1[3]);
            akey[ds] = pk.v8;
        }
    }

    // Per-lane row metadata (C/D layout: row = 4*lhi + r, col = l15)
    int gr[4], rb[4], rk[4], msk[4];
    float cfr[4][CONV_CH];
    #pragma unroll
    for (int r = 0; r < 4; r++) {
        gr[r] = wrow0 + 4 * lhi + r;
        rb[r] = gr[r] / KLEN;
        rk[r] = gr[r] % KLEN;
        msk[r] = mask[rb[r] * KLEN + rk[r]];
        #pragma unroll
        for (int c = 0; c < CONV_CH; c++)
            cfr[r][c] = cf[((size_t)rb[r] * CONV_CH + c) * KLEN + rk[r]];
    }

    float pe[4] = {0.f, 0.f, 0.f, 0.f};

    for (int a0 = 0; a0 < ADIM; a0 += 16) {
        // cooperative swizzled store of Wk tile [16][512] bf16
        #pragma unroll
        for (int it = 0; it < 4; it++) {
            int ch = tid + it * 256;          // 0..1023 chunks of 16B
            int arow = ch >> 6, col8 = ch & 63;
            uint4 data = *(const uint4*)(wkb + (size_t)(a0 + arow) * KDIM + col8 * 8);
            int off = (arow << 10) + (col8 << 4);
            off ^= (arow & 7) << 4;
            *(uint4*)(smem + off) = data;
        }
        __syncthreads();

        f32x4 acc = {0.f, 0.f, 0.f, 0.f};
        #pragma unroll
        for (int ds = 0; ds < 16; ds++) {
            int off = (l15 << 10) + (ds << 6) + (lhi << 4);
            off ^= (l15 & 7) << 4;
            bf16x8 bfrag = *(const bf16x8*)(smem + off);
            acc = __builtin_amdgcn_mfma_f32_16x16x32_bf16(akey[ds], bfrag, acc, 0, 0, 0);
        }

        // epilogue: bias + qproj + conv_proj, tanh, dot with v
        int a = a0 + l15;
        float bka = bk[a], va = vvec[a];
        float wc[CONV_CH];
        #pragma unroll
        for (int c = 0; c < CONV_CH; c++) wc[c] = Wconv[a * CONV_CH + c];
        #pragma unroll
        for (int r = 0; r < 4; r++) {
            float x = acc[r] + bka + qproj[rb[r] * ADIM + a];
            #pragma unroll
            for (int c = 0; c < CONV_CH; c++) x += wc[c] * cfr[r][c];
            pe[r] += fast_tanh(x) * va;
        }
        __syncthreads();
    }

    // reduce over the 16 lanes holding different a-columns
    #pragma unroll
    for (int r = 0; r < 4; r++) {
        float s = pe[r];
        s += __shfl_xor(s, 1);
        s += __shfl_xor(s, 2);
        s += __shfl_xor(s, 4);
        s += __shfl_xor(s, 8);
        pe[r] = s;
    }
    if (l15 == 0) {
        #pragma unroll
        for (int r = 0; r < 4; r++)
            e_out[gr[r]] = msk[r] ? pe[r] : -3.4028235e38f;
    }
}

// ---- K4: row softmax -> aw ----------------------------------------------
__global__ void k_softmax(const float* __restrict__ e, float* __restrict__ aw) {
    int b = blockIdx.x;
    const float* er = e + b * KLEN;
    __shared__ float redm[4], reds[4];
    int tid = threadIdx.x, lane = tid & 63, wv = tid >> 6;
    float m = -3.4028235e38f;
    for (int k = tid; k < KLEN; k += 256) m = fmaxf(m, er[k]);
    for (int o = 32; o; o >>= 1) m = fmaxf(m, __shfl_xor(m, o));
    if (lane == 0) redm[wv] = m;
    __syncthreads();
    m = fmaxf(fmaxf(redm[0], redm[1]), fmaxf(redm[2], redm[3]));
    float s = 0.f;
    for (int k = tid; k < KLEN; k += 256) s += __expf(er[k] - m);
    for (int o = 32; o; o >>= 1) s += __shfl_xor(s, o);
    if (lane == 0) reds[wv] = s;
    __syncthreads();
    s = reds[0] + reds[1] + reds[2] + reds[3];
    float inv = 1.0f / s;
    for (int k = tid; k < KLEN; k += 256) aw[b * KLEN + k] = __expf(er[k] - m) * inv;
}

// ---- K5a: partial cv over k-chunks --------------------------------------
__global__ void k_cvpart(const float* __restrict__ aw, const float* __restrict__ value,
                         float* __restrict__ part) {
    int b = blockIdx.x >> 3, chunk = blockIdx.x & 7;
    int k0 = chunk * 250;
    __shared__ float sa[250];
    int tid = threadIdx.x;
    if (tid < 250) sa[tid] = aw[b * KLEN + k0 + tid];
    __syncthreads();
    const float* vp = value + ((size_t)b * KLEN + k0) * VDIM + tid * 2;
    float ax = 0.f, ay = 0.f;
    #pragma unroll 5
    for (int k = 0; k < 250; k++) {
        const float2 vv = *(const float2*)(vp + (size_t)k * VDIM);
        ax += sa[k] * vv.x; ay += sa[k] * vv.y;
    }
    float2 o; o.x = ax; o.y = ay;
    *(float2*)(part + ((b * 8 + chunk) * VDIM) + tid * 2) = o;
}

// ---- K5b: reduce partials -> cv -----------------------------------------
__global__ void k_cvreduce(const float* __restrict__ part, float* __restrict__ cv) {
    int t = blockIdx.x * 256 + threadIdx.x;  // 16384
    int b = t >> 9, col = t & 511;
    float s = 0.f;
    #pragma unroll
    for (int c = 0; c < 8; c++) s += part[(b * 8 + c) * VDIM + col];
    cv[t] = s;
}

extern "C" void kernel_launch(void* const* d_in, const int* in_sizes, int n_in,
                              void* d_out, int out_size, void* d_ws, size_t ws_size,
                              hipStream_t stream) {
    const float* key     = (const float*)d_in[0];
    const float* value   = (const float*)d_in[1];
    const float* query   = (const float*)d_in[2];
    const float* aw_prev = (const float*)d_in[3];
    const int*   mask    = (const int*)d_in[4];
    const float* Wk      = (const float*)d_in[5];
    const float* bk      = (const float*)d_in[6];
    const float* Wq      = (const float*)d_in[7];
    const float* conv_w  = (const float*)d_in[8];
    const float* Wconv   = (const float*)d_in[9];
    const float* vvec    = (const float*)d_in[10];

    char* ws = (char*)d_ws;
    ushort* wkb  = (ushort*)(ws + 0);          // 512*512*2       = 524288
    float* qproj = (float*)(ws + 524288);      // 32*512*4        = 65536
    float* cf    = (float*)(ws + 589824);      // 32*10*2000*4    = 2560000
    float* e     = (float*)(ws + 3149824);     // 32*2000*4       = 256000
    float* part  = (float*)(ws + 3405824);     // 32*8*512*4      = 524288

    float* cv = (float*)d_out;                 // [32][512]
    float* aw = (float*)d_out + B * VDIM;      // [32][2000]

    k_cvt_wk  <<<1024, 256, 0, stream>>>(Wk, wkb);
    k_qproj   <<<64,   256, 0, stream>>>(query, Wq, qproj);
    k_conv    <<<2500, 256, 0, stream>>>(aw_prev, conv_w, cf);
    k_main    <<<1000, 256, 0, stream>>>(key, wkb, qproj, cf, bk, vvec, Wconv, mask, e);
    k_softmax <<<B,    256, 0, stream>>>(e, aw);
    k_cvpart  <<<B*8,  256, 0, stream>>>(aw, value, part);
    k_cvreduce<<<64,   256, 0, stream>>>(part, cv);
}

// Round 3
// 376.990 us; speedup vs baseline: 1.1823x; 1.1823x over previous
//
#include <hip/hip_runtime.h>
#include <hip/hip_bf16.h>
#include <math.h>

#define B 32
#define KLEN 2000
#define KDIM 512
#define QDIM 512
#define ADIM 512
#define VDIM 512
#define CONV_CH 10
#define CONV_K 201
#define NROWS (B*KLEN)

typedef __attribute__((ext_vector_type(8))) short bf16x8;
typedef __attribute__((ext_vector_type(4))) float f32x4;
typedef __attribute__((ext_vector_type(2))) float f32x2;

__device__ __forceinline__ ushort f32_to_bf16(float f) {
    union { float f; unsigned int u; } v; v.f = f;
    unsigned int x = v.u;
    unsigned int r = (x + 0x7FFFu + ((x >> 16) & 1u)) >> 16;
    return (ushort)r;
}

__device__ __forceinline__ float fast_tanh(float x) {
    // tanh(x) = 1 - 2/(e^(2x)+1); stable at both extremes (inf -> 1, -inf -> -1)
    return 1.0f - 2.0f / (__expf(2.0f * x) + 1.0f);
}

// ---- K0: Wk f32 -> bf16 -------------------------------------------------
__global__ void k_cvt_wk(const float* __restrict__ Wk, ushort* __restrict__ wkb) {
    int i = blockIdx.x * 256 + threadIdx.x;
    if (i < ADIM * KDIM) wkb[i] = f32_to_bf16(Wk[i]);
}

// ---- K1: qproj[b][a] = dot(query[b], Wq[a]) -----------------------------
__global__ void k_qproj(const float* __restrict__ query, const float* __restrict__ Wq,
                        float* __restrict__ qproj) {
    int t = blockIdx.x * 256 + threadIdx.x;        // 16384
    int b = t >> 9, a = t & 511;
    const f32x4* q = (const f32x4*)(query + b * QDIM);
    const f32x4* w = (const f32x4*)(Wq + a * QDIM);
    float acc = 0.f;
    #pragma unroll 4
    for (int i = 0; i < 128; i++) {
        f32x4 qv = q[i], wv = w[i];
        acc += qv[0]*wv[0] + qv[1]*wv[1] + qv[2]*wv[2] + qv[3]*wv[3];
    }
    qproj[t] = acc;
}

// ---- K2: conv_feat[b][c][k] = SAME cross-correlation --------------------
__global__ void k_conv(const float* __restrict__ aw_prev, const float* __restrict__ conv_w,
                       float* __restrict__ cf) {
    int t = blockIdx.x * 256 + threadIdx.x;
    if (t >= B * CONV_CH * KLEN) return;
    int k = t % KLEN;
    int c = (t / KLEN) % CONV_CH;
    int b = t / (KLEN * CONV_CH);
    const float* aw = aw_prev + b * KLEN;
    const float* w  = conv_w + c * CONV_K;
    int lo = k - 100;
    int t0 = lo < 0 ? -lo : 0;
    int t1 = (lo + CONV_K > KLEN) ? (KLEN - lo) : CONV_K;
    float acc = 0.f;
    for (int tt = t0; tt < t1; tt++) acc += w[tt] * aw[lo + tt];
    cf[t] = acc;
}

// ---- K3: fused kproj GEMM + additive score ------------------------------
// e[b][k] = sum_a v[a] * tanh(kproj + bk[a] + qproj[b][a] + sum_c cf[b][c][k]*Wconv[a][c])
__global__ __launch_bounds__(256, 4)
void k_main(const float* __restrict__ key, const ushort* __restrict__ wkb,
            const float* __restrict__ qproj, const float* __restrict__ cf,
            const float* __restrict__ bk, const float* __restrict__ vvec,
            const float* __restrict__ Wconv, const int* __restrict__ mask,
            float* __restrict__ e_out) {
    __shared__ char smem[16 * 1024];          // 16 a-rows x 512 d bf16, XOR-swizzled
    __shared__ float scf[CONV_CH][64];        // conv feats for the block's 64 rows
    const int tid  = threadIdx.x;
    const int wave = tid >> 6, lane = tid & 63;
    const int l15 = lane & 15, lhi = lane >> 4;
    const int row0 = blockIdx.x * 64;
    const int wrow0 = row0 + wave * 16;

    // stage conv features for this block's rows into LDS (saves 40 VGPRs/lane)
    for (int i = tid; i < 64 * CONV_CH; i += 256) {
        int rr = i & 63, c = i >> 6;
        int grow = row0 + rr, b = grow / KLEN, k = grow % KLEN;
        scf[c][rr] = __builtin_nontemporal_load(&cf[((size_t)b * CONV_CH + c) * KLEN + k]);
    }

    // Key fragments into registers (bf16, 64 VGPRs). A-frag: row=l15, k=ds*32+lhi*8+j
    // Non-temporal: key is streamed exactly once; keep L2 for wkb re-reads.
    bf16x8 akey[16];
    {
        const float* kp = key + (size_t)(wrow0 + l15) * KDIM + lhi * 8;
        #pragma unroll
        for (int ds = 0; ds < 16; ds++) {
            f32x4 f0 = __builtin_nontemporal_load((const f32x4*)(kp + ds * 32));
            f32x4 f1 = __builtin_nontemporal_load((const f32x4*)(kp + ds * 32 + 4));
            union { bf16x8 v8; ushort u[8]; } pk;
            pk.u[0] = f32_to_bf16(f0[0]); pk.u[1] = f32_to_bf16(f0[1]);
            pk.u[2] = f32_to_bf16(f0[2]); pk.u[3] = f32_to_bf16(f0[3]);
            pk.u[4] = f32_to_bf16(f1[0]); pk.u[5] = f32_to_bf16(f1[1]);
            pk.u[6] = f32_to_bf16(f1[2]); pk.u[7] = f32_to_bf16(f1[3]);
            akey[ds] = pk.v8;
        }
    }

    // Per-lane row metadata (C/D layout: row = 4*lhi + r, col = l15)
    int rb[4], rk[4];
    #pragma unroll
    for (int r = 0; r < 4; r++) {
        int gr = wrow0 + 4 * lhi + r;
        rb[r] = gr / KLEN;
        rk[r] = gr % KLEN;
    }
    __syncthreads();

    float pe[4] = {0.f, 0.f, 0.f, 0.f};

    for (int a0 = 0; a0 < ADIM; a0 += 16) {
        // cooperative swizzled store of Wk tile [16][512] bf16 (wants L2 hits)
        #pragma unroll
        for (int it = 0; it < 4; it++) {
            int ch = tid + it * 256;          // 0..1023 chunks of 16B
            int arow = ch >> 6, col8 = ch & 63;
            uint4 data = *(const uint4*)(wkb + (size_t)(a0 + arow) * KDIM + col8 * 8);
            int off = (arow << 10) + (col8 << 4);
            off ^= (arow & 7) << 4;
            *(uint4*)(smem + off) = data;
        }
        __syncthreads();

        f32x4 acc = {0.f, 0.f, 0.f, 0.f};
        #pragma unroll
        for (int ds = 0; ds < 16; ds++) {
            int off = (l15 << 10) + (ds << 6) + (lhi << 4);
            off ^= (l15 & 7) << 4;
            bf16x8 bfrag = *(const bf16x8*)(smem + off);
            acc = __builtin_amdgcn_mfma_f32_16x16x32_bf16(akey[ds], bfrag, acc, 0, 0, 0);
        }

        // epilogue: bias + qproj + conv_proj, tanh, dot with v
        int a = a0 + l15;
        float bka = bk[a], va = vvec[a];
        float wc[CONV_CH];
        #pragma unroll
        for (int c = 0; c < CONV_CH; c++) wc[c] = Wconv[a * CONV_CH + c];
        #pragma unroll
        for (int r = 0; r < 4; r++) {
            int widx = wave * 16 + 4 * lhi + r;
            float x = acc[r] + bka + qproj[rb[r] * ADIM + a];
            #pragma unroll
            for (int c = 0; c < CONV_CH; c++) x += wc[c] * scf[c][widx];
            pe[r] += fast_tanh(x) * va;
        }
        __syncthreads();
    }

    // reduce over the 16 lanes holding different a-columns
    #pragma unroll
    for (int r = 0; r < 4; r++) {
        float s = pe[r];
        s += __shfl_xor(s, 1);
        s += __shfl_xor(s, 2);
        s += __shfl_xor(s, 4);
        s += __shfl_xor(s, 8);
        pe[r] = s;
    }
    if (l15 == 0) {
        #pragma unroll
        for (int r = 0; r < 4; r++) {
            int gr = wrow0 + 4 * lhi + r;
            int m = mask[rb[r] * KLEN + rk[r]];
            e_out[gr] = m ? pe[r] : -3.4028235e38f;
        }
    }
}

// ---- K4: row softmax -> aw ----------------------------------------------
__global__ void k_softmax(const float* __restrict__ e, float* __restrict__ aw) {
    int b = blockIdx.x;
    const float* er = e + b * KLEN;
    __shared__ float redm[4], reds[4];
    int tid = threadIdx.x, lane = tid & 63, wv = tid >> 6;
    float m = -3.4028235e38f;
    for (int k = tid; k < KLEN; k += 256) m = fmaxf(m, er[k]);
    for (int o = 32; o; o >>= 1) m = fmaxf(m, __shfl_xor(m, o));
    if (lane == 0) redm[wv] = m;
    __syncthreads();
    m = fmaxf(fmaxf(redm[0], redm[1]), fmaxf(redm[2], redm[3]));
    float s = 0.f;
    for (int k = tid; k < KLEN; k += 256) s += __expf(er[k] - m);
    for (int o = 32; o; o >>= 1) s += __shfl_xor(s, o);
    if (lane == 0) reds[wv] = s;
    __syncthreads();
    s = reds[0] + reds[1] + reds[2] + reds[3];
    float inv = 1.0f / s;
    for (int k = tid; k < KLEN; k += 256) aw[b * KLEN + k] = __expf(er[k] - m) * inv;
}

// ---- K5a: partial cv over k-chunks --------------------------------------
__global__ void k_cvpart(const float* __restrict__ aw, const float* __restrict__ value,
                         float* __restrict__ part) {
    int b = blockIdx.x >> 3, chunk = blockIdx.x & 7;
    int k0 = chunk * 250;
    __shared__ float sa[250];
    int tid = threadIdx.x;
    if (tid < 250) sa[tid] = aw[b * KLEN + k0 + tid];
    __syncthreads();
    const float* vp = value + ((size_t)b * KLEN + k0) * VDIM + tid * 2;
    float ax = 0.f, ay = 0.f;
    #pragma unroll 5
    for (int k = 0; k < 250; k++) {
        const f32x2 vv = __builtin_nontemporal_load((const f32x2*)(vp + (size_t)k * VDIM));
        ax += sa[k] * vv[0]; ay += sa[k] * vv[1];
    }
    f32x2 o; o[0] = ax; o[1] = ay;
    *(f32x2*)(part + ((b * 8 + chunk) * VDIM) + tid * 2) = o;
}

// ---- K5b: reduce partials -> cv -----------------------------------------
__global__ void k_cvreduce(const float* __restrict__ part, float* __restrict__ cv) {
    int t = blockIdx.x * 256 + threadIdx.x;  // 16384
    int b = t >> 9, col = t & 511;
    float s = 0.f;
    #pragma unroll
    for (int c = 0; c < 8; c++) s += part[(b * 8 + c) * VDIM + col];
    cv[t] = s;
}

extern "C" void kernel_launch(void* const* d_in, const int* in_sizes, int n_in,
                              void* d_out, int out_size, void* d_ws, size_t ws_size,
                              hipStream_t stream) {
    const float* key     = (const float*)d_in[0];
    const float* value   = (const float*)d_in[1];
    const float* query   = (const float*)d_in[2];
    const float* aw_prev = (const float*)d_in[3];
    const int*   mask    = (const int*)d_in[4];
    const float* Wk      = (const float*)d_in[5];
    const float* bk      = (const float*)d_in[6];
    const float* Wq      = (const float*)d_in[7];
    const float* conv_w  = (const float*)d_in[8];
    const float* Wconv   = (const float*)d_in[9];
    const float* vvec    = (const float*)d_in[10];

    char* ws = (char*)d_ws;
    ushort* wkb  = (ushort*)(ws + 0);          // 512*512*2       = 524288
    float* qproj = (float*)(ws + 524288);      // 32*512*4        = 65536
    float* cf    = (float*)(ws + 589824);      // 32*10*2000*4    = 2560000
    float* e     = (float*)(ws + 3149824);     // 32*2000*4       = 256000
    float* part  = (float*)(ws + 3405824);     // 32*8*512*4      = 524288

    float* cv = (float*)d_out;                 // [32][512]
    float* aw = (float*)d_out + B * VDIM;      // [32][2000]

    k_cvt_wk  <<<1024, 256, 0, stream>>>(Wk, wkb);
    k_qproj   <<<64,   256, 0, stream>>>(query, Wq, qproj);
    k_conv    <<<2500, 256, 0, stream>>>(aw_prev, conv_w, cf);
    k_main    <<<1000, 256, 0, stream>>>(key, wkb, qproj, cf, bk, vvec, Wconv, mask, e);
    k_softmax <<<B,    256, 0, stream>>>(e, aw);
    k_cvpart  <<<B*8,  256, 0, stream>>>(aw, value, part);
    k_cvreduce<<<64,   256, 0, stream>>>(part, cv);
}

// Round 4
// 252.769 us; speedup vs baseline: 1.7634x; 1.4914x over previous
//
#include <hip/hip_runtime.h>
#include <hip/hip_bf16.h>
#include <math.h>

#define B 32
#define KLEN 2000
#define KDIM 512
#define QDIM 512
#define ADIM 512
#define VDIM 512
#define CONV_CH 10
#define CONV_K 201

#define KEXT 528                 // 512 key + 10 conv + 1 bias-one + 5 zero pad
#define NKS  33                  // KEXT / 16
#define CT_N 16                  // 512 / 32 col-tiles
#define TILE_BYTES (NKS * 1024)  // 33 ks x 32 rows x 16 k x 2B = 33792

typedef __attribute__((ext_vector_type(8)))  short bf16x8;
typedef __attribute__((ext_vector_type(16))) float f32x16;
typedef __attribute__((ext_vector_type(4)))  float f32x4;
typedef __attribute__((ext_vector_type(2)))  float f32x2;

__device__ __forceinline__ ushort f32_to_bf16(float f) {
    union { float f; unsigned int u; } v; v.f = f;
    unsigned int x = v.u;
    unsigned int r = (x + 0x7FFFu + ((x >> 16) & 1u)) >> 16;
    return (ushort)r;
}

__device__ __forceinline__ float fast_tanh(float x) {
    // tanh(x) = 1 - 2/(e^(2x)+1); stable at both extremes
    return 1.0f - 2.0f / (__expf(2.0f * x) + 1.0f);
}

// ---- K0: pack W_ext = [Wk | Wconv | bk | 0pad] into MFMA-B tile layout ----
// layout: [ct(16)][ks(33)][r(32)][kk(16)] bf16; a = ct*32+r, j = ks*16+kk
__global__ void k_pack_w(const float* __restrict__ Wk, const float* __restrict__ Wconv,
                         const float* __restrict__ bk, ushort* __restrict__ wp) {
    int t = blockIdx.x * 256 + threadIdx.x;        // 33792 16B-chunks
    int h = t & 1;
    int idx = t >> 1;
    int r = idx & 31;
    int idx2 = idx >> 5;
    int ks = idx2 % 33, ct = idx2 / 33;
    int a = ct * 32 + r;
    int j0 = ks * 16 + h * 8;
    union { uint4 v; ushort u[8]; } pk;
    #pragma unroll
    for (int jj = 0; jj < 8; jj++) {
        int j = j0 + jj;
        float val;
        if (j < 512)      val = Wk[a * KDIM + j];
        else if (j < 522) val = Wconv[a * CONV_CH + (j - 512)];
        else if (j == 522) val = bk[a];
        else              val = 0.f;
        pk.u[jj] = f32_to_bf16(val);
    }
    *(uint4*)(wp + (size_t)t * 8) = pk.v;
}

// ---- K1: qproj[b][a] = dot(query[b], Wq[a]) -----------------------------
__global__ void k_qproj(const float* __restrict__ query, const float* __restrict__ Wq,
                        float* __restrict__ qproj) {
    int t = blockIdx.x * 256 + threadIdx.x;        // 16384
    int b = t >> 9, a = t & 511;
    const f32x4* q = (const f32x4*)(query + b * QDIM);
    const f32x4* w = (const f32x4*)(Wq + a * QDIM);
    float acc = 0.f;
    #pragma unroll 4
    for (int i = 0; i < 128; i++) {
        f32x4 qv = q[i], wv = w[i];
        acc += qv[0]*wv[0] + qv[1]*wv[1] + qv[2]*wv[2] + qv[3]*wv[3];
    }
    qproj[t] = acc;
}

// ---- K2: conv_feat[b][c][k] = SAME cross-correlation --------------------
__global__ void k_conv(const float* __restrict__ aw_prev, const float* __restrict__ conv_w,
                       float* __restrict__ cf) {
    int t = blockIdx.x * 256 + threadIdx.x;
    if (t >= B * CONV_CH * KLEN) return;
    int k = t % KLEN;
    int c = (t / KLEN) % CONV_CH;
    int b = t / (KLEN * CONV_CH);
    const float* aw = aw_prev + b * KLEN;
    const float* w  = conv_w + c * CONV_K;
    int lo = k - 100;
    int t0 = lo < 0 ? -lo : 0;
    int t1 = (lo + CONV_K > KLEN) ? (KLEN - lo) : CONV_K;
    float acc = 0.f;
    for (int tt = t0; tt < t1; tt++) acc += w[tt] * aw[lo + tt];
    cf[t] = acc;
}

// ---- K3: fused kproj-ext GEMM + additive score --------------------------
// e[row] = sum_a v[a] * tanh( [key|cf|1]row . Wext_a + qproj[b][a] )
__global__ __launch_bounds__(256, 2)
void k_main(const float* __restrict__ key, const ushort* __restrict__ wp,
            const float* __restrict__ qproj, const float* __restrict__ cf,
            const float* __restrict__ vvec, const int* __restrict__ mask,
            float* __restrict__ e_out) {
    __shared__ char smem[2 * TILE_BYTES];          // 67.5 KB double-buffered B tile
    const int tid  = threadIdx.x;
    const int wave = tid >> 6, lane = tid & 63;
    const int r = lane & 31, h = lane >> 5;
    const int wrow0 = blockIdx.x * 128 + wave * 32;

    // ---- A fragments: this wave's 32 rows x 528 k, bf16, registers ------
    bf16x8 A[NKS];
    {
        const int grow = wrow0 + r;
        const float* kp = key + (size_t)grow * KDIM + h * 8;
        #pragma unroll
        for (int ks = 0; ks < 32; ks++) {
            f32x4 f0 = __builtin_nontemporal_load((const f32x4*)(kp + ks * 16));
            f32x4 f1 = __builtin_nontemporal_load((const f32x4*)(kp + ks * 16 + 4));
            union { bf16x8 v8; ushort u[8]; } pk;
            pk.u[0] = f32_to_bf16(f0[0]); pk.u[1] = f32_to_bf16(f0[1]);
            pk.u[2] = f32_to_bf16(f0[2]); pk.u[3] = f32_to_bf16(f0[3]);
            pk.u[4] = f32_to_bf16(f1[0]); pk.u[5] = f32_to_bf16(f1[1]);
            pk.u[6] = f32_to_bf16(f1[2]); pk.u[7] = f32_to_bf16(f1[3]);
            A[ks] = pk.v8;
        }
        // ks=32: j = 512 + h*8 + jj -> cf[0..9], 1.0, zeros
        int b_a = grow / KLEN, kpos = grow % KLEN;
        const float* cfb = cf + ((size_t)b_a * CONV_CH) * KLEN + kpos;
        union { bf16x8 v8; ushort u[8]; } pk;
        if (h == 0) {
            #pragma unroll
            for (int jj = 0; jj < 8; jj++) pk.u[jj] = f32_to_bf16(cfb[(size_t)jj * KLEN]);
        } else {
            pk.u[0] = f32_to_bf16(cfb[(size_t)8 * KLEN]);
            pk.u[1] = f32_to_bf16(cfb[(size_t)9 * KLEN]);
            pk.u[2] = 0x3F80;  // 1.0f in bf16
            pk.u[3] = 0; pk.u[4] = 0; pk.u[5] = 0; pk.u[6] = 0; pk.u[7] = 0;
        }
        A[32] = pk.v8;
    }

    // epilogue row metadata: C/D rows for this lane = base + pat[i]
    const int base = wrow0 + 4 * h;
    const int b_lo = base / KLEN;
    const int b_hi = (base + 27) / KLEN;
    const int split = (b_lo + 1) * KLEN - base;    // pat >= split -> b_hi

    // ---- prologue: stage col-tile 0 into buffer 0 -----------------------
    {
        const char* src = (const char*)wp;
        #pragma unroll
        for (int i = 0; i < 8; i++) {
            int ch = tid + i * 256;
            *(uint4*)(smem + ch * 16) = *(const uint4*)(src + (size_t)ch * 16);
        }
        if (tid < 64) {
            int ch = tid + 2048;
            *(uint4*)(smem + ch * 16) = *(const uint4*)(src + (size_t)ch * 16);
        }
    }
    __syncthreads();

    float pe[16];
    #pragma unroll
    for (int i = 0; i < 16; i++) pe[i] = 0.f;

    for (int ct = 0; ct < CT_N; ct++) {
        // issue prefetch loads for next col-tile (hidden under MFMA)
        uint4 st[8]; uint4 st8;
        const bool pf = (ct + 1 < CT_N);
        const char* src = (const char*)wp + (size_t)(ct + 1) * TILE_BYTES;
        if (pf) {
            #pragma unroll
            for (int i = 0; i < 8; i++) st[i] = *(const uint4*)(src + (size_t)(tid + i * 256) * 16);
            if (tid < 64) st8 = *(const uint4*)(src + (size_t)(tid + 2048) * 16);
        }

        // MFMA over K on current buffer
        const char* sb = smem + (ct & 1) * TILE_BYTES;
        const int boff = r * 32 + h * 16;
        f32x16 acc0 = {0,0,0,0,0,0,0,0,0,0,0,0,0,0,0,0};
        f32x16 acc1 = {0,0,0,0,0,0,0,0,0,0,0,0,0,0,0,0};
        #pragma unroll
        for (int ks = 0; ks < NKS; ks++) {
            bf16x8 bfrag = *(const bf16x8*)(sb + ks * 1024 + boff);
            if (ks & 1) acc1 = __builtin_amdgcn_mfma_f32_32x32x16_bf16(A[ks], bfrag, acc1, 0, 0, 0);
            else        acc0 = __builtin_amdgcn_mfma_f32_32x32x16_bf16(A[ks], bfrag, acc0, 0, 0, 0);
        }

        // epilogue: + qproj, tanh, * v, accumulate
        const int col = ct * 32 + r;
        const float va = vvec[col];
        const float qa = qproj[b_lo * ADIM + col];
        const float qb = (b_hi != b_lo) ? qproj[b_hi * ADIM + col] : qa;
        #pragma unroll
        for (int i = 0; i < 16; i++) {
            const int pat = (i & 3) + 8 * (i >> 2);
            float q = (pat >= split) ? qb : qa;
            float x = acc0[i] + acc1[i] + q;
            pe[i] += fast_tanh(x) * va;
        }

        // write prefetched tile into the other buffer
        if (pf) {
            char* dst = smem + ((ct + 1) & 1) * TILE_BYTES;
            #pragma unroll
            for (int i = 0; i < 8; i++) *(uint4*)(dst + (tid + i * 256) * 16) = st[i];
            if (tid < 64) *(uint4*)(dst + (tid + 2048) * 16) = st8;
        }
        __syncthreads();
    }

    // reduce over the 32 lanes (cols) sharing the same row set
    float red[16];
    #pragma unroll
    for (int i = 0; i < 16; i++) {
        float s = pe[i];
        s += __shfl_xor(s, 1);
        s += __shfl_xor(s, 2);
        s += __shfl_xor(s, 4);
        s += __shfl_xor(s, 8);
        s += __shfl_xor(s, 16);
        red[i] = s;
    }
    if (r == 0) {
        #pragma unroll
        for (int i = 0; i < 16; i++) {
            const int pat = (i & 3) + 8 * (i >> 2);
            int grow = base + pat;
            e_out[grow] = mask[grow] ? red[i] : -3.4028235e38f;
        }
    }
}

// ---- K4: row softmax -> aw ----------------------------------------------
__global__ void k_softmax(const float* __restrict__ e, float* __restrict__ aw) {
    int b = blockIdx.x;
    const float* er = e + b * KLEN;
    __shared__ float redm[4], reds[4];
    int tid = threadIdx.x, lane = tid & 63, wv = tid >> 6;
    float m = -3.4028235e38f;
    for (int k = tid; k < KLEN; k += 256) m = fmaxf(m, er[k]);
    for (int o = 32; o; o >>= 1) m = fmaxf(m, __shfl_xor(m, o));
    if (lane == 0) redm[wv] = m;
    __syncthreads();
    m = fmaxf(fmaxf(redm[0], redm[1]), fmaxf(redm[2], redm[3]));
    float s = 0.f;
    for (int k = tid; k < KLEN; k += 256) s += __expf(er[k] - m);
    for (int o = 32; o; o >>= 1) s += __shfl_xor(s, o);
    if (lane == 0) reds[wv] = s;
    __syncthreads();
    s = reds[0] + reds[1] + reds[2] + reds[3];
    float inv = 1.0f / s;
    for (int k = tid; k < KLEN; k += 256) aw[b * KLEN + k] = __expf(er[k] - m) * inv;
}

// ---- K5a: partial cv over 16 k-chunks of 125 ----------------------------
__global__ void k_cvpart(const float* __restrict__ aw, const float* __restrict__ value,
                         float* __restrict__ part) {
    int b = blockIdx.x >> 4, chunk = blockIdx.x & 15;
    int k0 = chunk * 125;
    __shared__ float sa[125];
    int tid = threadIdx.x;
    if (tid < 125) sa[tid] = aw[b * KLEN + k0 + tid];
    __syncthreads();
    const float* vp = value + ((size_t)b * KLEN + k0) * VDIM + tid * 2;
    float ax = 0.f, ay = 0.f;
    #pragma unroll 5
    for (int k = 0; k < 125; k++) {
        const f32x2 vv = __builtin_nontemporal_load((const f32x2*)(vp + (size_t)k * VDIM));
        ax += sa[k] * vv[0]; ay += sa[k] * vv[1];
    }
    f32x2 o; o[0] = ax; o[1] = ay;
    *(f32x2*)(part + ((b * 16 + chunk) * VDIM) + tid * 2) = o;
}

// ---- K5b: reduce partials -> cv -----------------------------------------
__global__ void k_cvreduce(const float* __restrict__ part, float* __restrict__ cv) {
    int t = blockIdx.x * 256 + threadIdx.x;  // 16384
    int b = t >> 9, col = t & 511;
    float s = 0.f;
    #pragma unroll
    for (int c = 0; c < 16; c++) s += part[(b * 16 + c) * VDIM + col];
    cv[t] = s;
}

extern "C" void kernel_launch(void* const* d_in, const int* in_sizes, int n_in,
                              void* d_out, int out_size, void* d_ws, size_t ws_size,
                              hipStream_t stream) {
    const float* key     = (const float*)d_in[0];
    const float* value   = (const float*)d_in[1];
    const float* query   = (const float*)d_in[2];
    const float* aw_prev = (const float*)d_in[3];
    const int*   mask    = (const int*)d_in[4];
    const float* Wk      = (const float*)d_in[5];
    const float* bk      = (const float*)d_in[6];
    const float* Wq      = (const float*)d_in[7];
    const float* conv_w  = (const float*)d_in[8];
    const float* Wconv   = (const float*)d_in[9];
    const float* vvec    = (const float*)d_in[10];

    char* ws = (char*)d_ws;
    ushort* wp   = (ushort*)(ws + 0);          // 16*33*32*16*2 = 540672
    float* qproj = (float*)(ws + 540672);      // 32*512*4      = 65536
    float* cf    = (float*)(ws + 606208);      // 32*10*2000*4  = 2560000
    float* e     = (float*)(ws + 3166208);     // 32*2000*4     = 256000
    float* part  = (float*)(ws + 0);           // 32*16*512*4 = 1048576 (reuses wp/qproj/cf region, dead after k_main)

    float* cv = (float*)d_out;                 // [32][512]
    float* aw = (float*)d_out + B * VDIM;      // [32][2000]

    k_pack_w  <<<132,  256, 0, stream>>>(Wk, Wconv, bk, wp);
    k_qproj   <<<64,   256, 0, stream>>>(query, Wq, qproj);
    k_conv    <<<2500, 256, 0, stream>>>(aw_prev, conv_w, cf);
    k_main    <<<500,  256, 0, stream>>>(key, wp, qproj, cf, vvec, mask, e);
    k_softmax <<<B,    256, 0, stream>>>(e, aw);
    k_cvpart  <<<B*16, 256, 0, stream>>>(aw, value, part);
    k_cvreduce<<<64,   256, 0, stream>>>(part, cv);
}

// Round 5
// 215.044 us; speedup vs baseline: 2.0727x; 1.1754x over previous
//
#include <hip/hip_runtime.h>
#include <hip/hip_bf16.h>
#include <math.h>

#define B 32
#define KLEN 2000
#define KDIM 512
#define QDIM 512
#define ADIM 512
#define VDIM 512
#define CONV_CH 10
#define CONV_K 201

#define KEXT 528                 // 512 key + 10 conv + 1 bias-one + 5 zero pad
#define NKS  33                  // KEXT / 16
#define CT_N 16                  // 512 / 32 col-tiles
#define TILE_BYTES (NKS * 1024)  // 33 ks x 64 lanes x 16B = 33792

typedef __attribute__((ext_vector_type(8)))  short bf16x8;
typedef __attribute__((ext_vector_type(16))) float f32x16;
typedef __attribute__((ext_vector_type(4)))  float f32x4;
typedef __attribute__((ext_vector_type(2)))  float f32x2;

typedef const __attribute__((address_space(1))) unsigned int gu32;
typedef __attribute__((address_space(3))) unsigned int lu32;

__device__ __forceinline__ ushort f32_to_bf16(float f) {
    union { float f; unsigned int u; } v; v.f = f;
    unsigned int x = v.u;
    unsigned int r = (x + 0x7FFFu + ((x >> 16) & 1u)) >> 16;
    return (ushort)r;
}

__device__ __forceinline__ float fast_tanh(float x) {
    // tanh(x) = 1 - 2/(e^(2x)+1); stable at both extremes
    return 1.0f - 2.0f / (__expf(2.0f * x) + 1.0f);
}

// ---- K0: pack W_ext = [Wk | Wconv | bk | 0pad] into MFMA-B lane layout ----
// layout: [ct(16)][ks(33)][lane(64)][8 bf16]; lane = h*32+r;
// holds B[k = ks*16 + h*8 + jj][col = ct*32 + r]  (conflict-free ds_read at lane*16)
__global__ void k_pack_w(const float* __restrict__ Wk, const float* __restrict__ Wconv,
                         const float* __restrict__ bk, ushort* __restrict__ wp) {
    int t = blockIdx.x * 256 + threadIdx.x;        // 33792 16B-chunks
    int lane = t & 63;
    int idx = t >> 6;
    int ks = idx % NKS, ct = idx / NKS;
    int h = lane >> 5, r = lane & 31;
    int a = ct * 32 + r;
    int j0 = ks * 16 + h * 8;
    union { uint4 v; ushort u[8]; } pk;
    #pragma unroll
    for (int jj = 0; jj < 8; jj++) {
        int j = j0 + jj;
        float val;
        if (j < 512)       val = Wk[a * KDIM + j];
        else if (j < 522)  val = Wconv[a * CONV_CH + (j - 512)];
        else if (j == 522) val = bk[a];
        else               val = 0.f;
        pk.u[jj] = f32_to_bf16(val);
    }
    *(uint4*)(wp + (size_t)t * 8) = pk.v;
}

// ---- K1: qproj[b][a] = dot(query[b], Wq[a]) -----------------------------
__global__ void k_qproj(const float* __restrict__ query, const float* __restrict__ Wq,
                        float* __restrict__ qproj) {
    int t = blockIdx.x * 256 + threadIdx.x;        // 16384
    int b = t >> 9, a = t & 511;
    const f32x4* q = (const f32x4*)(query + b * QDIM);
    const f32x4* w = (const f32x4*)(Wq + a * QDIM);
    float acc = 0.f;
    #pragma unroll 4
    for (int i = 0; i < 128; i++) {
        f32x4 qv = q[i], wv = w[i];
        acc += qv[0]*wv[0] + qv[1]*wv[1] + qv[2]*wv[2] + qv[3]*wv[3];
    }
    qproj[t] = acc;
}

// ---- K2: conv_feat[b][c][k] = SAME cross-correlation --------------------
__global__ void k_conv(const float* __restrict__ aw_prev, const float* __restrict__ conv_w,
                       float* __restrict__ cf) {
    int t = blockIdx.x * 256 + threadIdx.x;
    if (t >= B * CONV_CH * KLEN) return;
    int k = t % KLEN;
    int c = (t / KLEN) % CONV_CH;
    int b = t / (KLEN * CONV_CH);
    const float* aw = aw_prev + b * KLEN;
    const float* w  = conv_w + c * CONV_K;
    int lo = k - 100;
    int t0 = lo < 0 ? -lo : 0;
    int t1 = (lo + CONV_K > KLEN) ? (KLEN - lo) : CONV_K;
    float acc = 0.f;
    for (int tt = t0; tt < t1; tt++) acc += w[tt] * aw[lo + tt];
    cf[t] = acc;
}

// ---- K3: fused kproj-ext GEMM + additive score --------------------------
// e[row] = sum_a v[a] * tanh( [key|cf|1]row . Wext_a + qproj[b][a] )
__global__ __launch_bounds__(256, 2)
void k_main(const float* __restrict__ key, const ushort* __restrict__ wp,
            const float* __restrict__ qproj, const float* __restrict__ cf,
            const float* __restrict__ vvec, const int* __restrict__ mask,
            float* __restrict__ e_out) {
    __shared__ char smem[2 * TILE_BYTES];          // 67.5 KB double-buffered B tile
    const int tid  = threadIdx.x;
    const int wave = tid >> 6, lane = tid & 63;
    const int r = lane & 31, h = lane >> 5;
    const int wrow0 = blockIdx.x * 128 + wave * 32;

    // ---- A fragments: this wave's 32 rows x 528 k, bf16, registers ------
    bf16x8 A[NKS];
    {
        const int grow = wrow0 + r;
        const float* kp = key + (size_t)grow * KDIM + h * 8;
        #pragma unroll
        for (int ks = 0; ks < 32; ks++) {
            f32x4 f0 = __builtin_nontemporal_load((const f32x4*)(kp + ks * 16));
            f32x4 f1 = __builtin_nontemporal_load((const f32x4*)(kp + ks * 16 + 4));
            union { bf16x8 v8; ushort u[8]; } pk;
            pk.u[0] = f32_to_bf16(f0[0]); pk.u[1] = f32_to_bf16(f0[1]);
            pk.u[2] = f32_to_bf16(f0[2]); pk.u[3] = f32_to_bf16(f0[3]);
            pk.u[4] = f32_to_bf16(f1[0]); pk.u[5] = f32_to_bf16(f1[1]);
            pk.u[6] = f32_to_bf16(f1[2]); pk.u[7] = f32_to_bf16(f1[3]);
            A[ks] = pk.v8;
        }
        // ks=32: j = 512 + h*8 + jj -> cf[0..9], 1.0, zeros
        int b_a = grow / KLEN, kpos = grow % KLEN;
        const float* cfb = cf + ((size_t)b_a * CONV_CH) * KLEN + kpos;
        union { bf16x8 v8; ushort u[8]; } pk;
        if (h == 0) {
            #pragma unroll
            for (int jj = 0; jj < 8; jj++) pk.u[jj] = f32_to_bf16(cfb[(size_t)jj * KLEN]);
        } else {
            pk.u[0] = f32_to_bf16(cfb[(size_t)8 * KLEN]);
            pk.u[1] = f32_to_bf16(cfb[(size_t)9 * KLEN]);
            pk.u[2] = 0x3F80;  // 1.0f in bf16
            pk.u[3] = 0; pk.u[4] = 0; pk.u[5] = 0; pk.u[6] = 0; pk.u[7] = 0;
        }
        A[32] = pk.v8;
    }

    // epilogue row metadata: C/D rows for this lane = base + pat[i]
    const int base = wrow0 + 4 * h;
    const int b_lo = base / KLEN;
    const int b_hi = (base + 27) / KLEN;
    const int split = (b_lo + 1) * KLEN - base;    // pat >= split -> b_hi

    // async stage of one col-tile into LDS buffer (no VGPR round-trip)
    auto stage = [&](int buf, int ct) {
        const char* src = (const char*)wp + (size_t)ct * TILE_BYTES + lane * 16;
        char* dst = smem + buf * TILE_BYTES;
        for (int ks = wave; ks < NKS; ks += 4) {
            __builtin_amdgcn_global_load_lds((gu32*)(src + ks * 1024),
                                             (lu32*)(dst + ks * 1024), 16, 0, 0);
        }
    };

    // ---- prologue: stage col-tile 0 into buffer 0 -----------------------
    stage(0, 0);
    __syncthreads();   // drains vmcnt before LDS read

    float pe[16];
    #pragma unroll
    for (int i = 0; i < 16; i++) pe[i] = 0.f;

    for (int ct = 0; ct < CT_N; ct++) {
        // issue async prefetch of next col-tile into the other buffer
        if (ct + 1 < CT_N) stage((ct + 1) & 1, ct + 1);

        // MFMA over K on current buffer; ds_read at lane*16 is conflict-free
        const char* sb = smem + (ct & 1) * TILE_BYTES + lane * 16;
        f32x16 acc0 = {0,0,0,0,0,0,0,0,0,0,0,0,0,0,0,0};
        f32x16 acc1 = {0,0,0,0,0,0,0,0,0,0,0,0,0,0,0,0};
        #pragma unroll
        for (int ks = 0; ks < NKS; ks++) {
            bf16x8 bfrag = *(const bf16x8*)(sb + ks * 1024);
            if (ks & 1) acc1 = __builtin_amdgcn_mfma_f32_32x32x16_bf16(A[ks], bfrag, acc1, 0, 0, 0);
            else        acc0 = __builtin_amdgcn_mfma_f32_32x32x16_bf16(A[ks], bfrag, acc0, 0, 0, 0);
        }

        // epilogue: + qproj, tanh, * v, accumulate
        const int col = ct * 32 + r;
        const float va = vvec[col];
        const float qa = qproj[b_lo * ADIM + col];
        const float qb = (b_hi != b_lo) ? qproj[b_hi * ADIM + col] : qa;
        #pragma unroll
        for (int i = 0; i < 16; i++) {
            const int pat = (i & 3) + 8 * (i >> 2);
            float q = (pat >= split) ? qb : qa;
            float x = acc0[i] + acc1[i] + q;
            pe[i] += fast_tanh(x) * va;
        }

        __syncthreads();   // vmcnt(0)+barrier: prefetch landed, buf safe to swap
    }

    // reduce over the 32 lanes (cols) sharing the same row set
    float red[16];
    #pragma unroll
    for (int i = 0; i < 16; i++) {
        float s = pe[i];
        s += __shfl_xor(s, 1);
        s += __shfl_xor(s, 2);
        s += __shfl_xor(s, 4);
        s += __shfl_xor(s, 8);
        s += __shfl_xor(s, 16);
        red[i] = s;
    }
    if (r == 0) {
        #pragma unroll
        for (int i = 0; i < 16; i++) {
            const int pat = (i & 3) + 8 * (i >> 2);
            int grow = base + pat;
            e_out[grow] = mask[grow] ? red[i] : -3.4028235e38f;
        }
    }
}

// ---- K4: row softmax -> aw ----------------------------------------------
__global__ void k_softmax(const float* __restrict__ e, float* __restrict__ aw) {
    int b = blockIdx.x;
    const float* er = e + b * KLEN;
    __shared__ float redm[4], reds[4];
    int tid = threadIdx.x, lane = tid & 63, wv = tid >> 6;
    float m = -3.4028235e38f;
    for (int k = tid; k < KLEN; k += 256) m = fmaxf(m, er[k]);
    for (int o = 32; o; o >>= 1) m = fmaxf(m, __shfl_xor(m, o));
    if (lane == 0) redm[wv] = m;
    __syncthreads();
    m = fmaxf(fmaxf(redm[0], redm[1]), fmaxf(redm[2], redm[3]));
    float s = 0.f;
    for (int k = tid; k < KLEN; k += 256) s += __expf(er[k] - m);
    for (int o = 32; o; o >>= 1) s += __shfl_xor(s, o);
    if (lane == 0) reds[wv] = s;
    __syncthreads();
    s = reds[0] + reds[1] + reds[2] + reds[3];
    float inv = 1.0f / s;
    for (int k = tid; k < KLEN; k += 256) aw[b * KLEN + k] = __expf(er[k] - m) * inv;
}

// ---- K5a: partial cv over 16 k-chunks of 125 ----------------------------
__global__ void k_cvpart(const float* __restrict__ aw, const float* __restrict__ value,
                         float* __restrict__ part) {
    int b = blockIdx.x >> 4, chunk = blockIdx.x & 15;
    int k0 = chunk * 125;
    __shared__ float sa[125];
    int tid = threadIdx.x;
    if (tid < 125) sa[tid] = aw[b * KLEN + k0 + tid];
    __syncthreads();
    const float* vp = value + ((size_t)b * KLEN + k0) * VDIM + tid * 2;
    float ax = 0.f, ay = 0.f;
    #pragma unroll 5
    for (int k = 0; k < 125; k++) {
        const f32x2 vv = __builtin_nontemporal_load((const f32x2*)(vp + (size_t)k * VDIM));
        ax += sa[k] * vv[0]; ay += sa[k] * vv[1];
    }
    f32x2 o; o[0] = ax; o[1] = ay;
    *(f32x2*)(part + ((b * 16 + chunk) * VDIM) + tid * 2) = o;
}

// ---- K5b: reduce partials -> cv -----------------------------------------
__global__ void k_cvreduce(const float* __restrict__ part, float* __restrict__ cv) {
    int t = blockIdx.x * 256 + threadIdx.x;  // 16384
    int b = t >> 9, col = t & 511;
    float s = 0.f;
    #pragma unroll
    for (int c = 0; c < 16; c++) s += part[(b * 16 + c) * VDIM + col];
    cv[t] = s;
}

extern "C" void kernel_launch(void* const* d_in, const int* in_sizes, int n_in,
                              void* d_out, int out_size, void* d_ws, size_t ws_size,
                              hipStream_t stream) {
    const float* key     = (const float*)d_in[0];
    const float* value   = (const float*)d_in[1];
    const float* query   = (const float*)d_in[2];
    const float* aw_prev = (const float*)d_in[3];
    const int*   mask    = (const int*)d_in[4];
    const float* Wk      = (const float*)d_in[5];
    const float* bk      = (const float*)d_in[6];
    const float* Wq      = (const float*)d_in[7];
    const float* conv_w  = (const float*)d_in[8];
    const float* Wconv   = (const float*)d_in[9];
    const float* vvec    = (const float*)d_in[10];

    char* ws = (char*)d_ws;
    ushort* wp   = (ushort*)(ws + 0);          // 16*33*64*8*2 = 540672
    float* qproj = (float*)(ws + 540672);      // 32*512*4     = 65536
    float* cf    = (float*)(ws + 606208);      // 32*10*2000*4 = 2560000
    float* e     = (float*)(ws + 3166208);     // 32*2000*4    = 256000
    float* part  = (float*)(ws + 3422208);     // 32*16*512*4  = 1048576

    float* cv = (float*)d_out;                 // [32][512]
    float* aw = (float*)d_out + B * VDIM;      // [32][2000]

    k_pack_w  <<<132,  256, 0, stream>>>(Wk, Wconv, bk, wp);
    k_qproj   <<<64,   256, 0, stream>>>(query, Wq, qproj);
    k_conv    <<<2500, 256, 0, stream>>>(aw_prev, conv_w, cf);
    k_main    <<<500,  256, 0, stream>>>(key, wp, qproj, cf, vvec, mask, e);
    k_softmax <<<B,    256, 0, stream>>>(e, aw);
    k_cvpart  <<<B*16, 256, 0, stream>>>(aw, value, part);
    k_cvreduce<<<64,   256, 0, stream>>>(part, cv);
}